// Round 2
// baseline (10888.688 us; speedup 1.0000x reference)
//
#include <hip/hip_runtime.h>

// Problem constants
#define BTOT 1024
#define TPTS 96
#define NV   7
#define HD   64
#define NH   256   // ode hidden (4*H)

// LDS layout (float offsets), total 20320 floats = 81280 B  (<= 81920 for 2 blocks/CU)
#define OFF_W1    0        // [64][256]            = 16384
#define OFF_HIDW  16384    // [4 waves][3][128]    = 1536
#define OFF_PARTS 17920    // [2 parity][4][3][64] = 1536
#define OFF_DECD  19456    // [4 waves][3][64]     = 768
#define OFF_TPS   20224    // 96
#define SMEM_FLOATS 20320
#define SMEM_BYTES  (SMEM_FLOATS * 4)

__device__ __forceinline__ float rdlane(float v, int i) {
    return __int_as_float(__builtin_amdgcn_readlane(__float_as_int(v), i));
}
__device__ __forceinline__ float wsum64(float v) {
    v += __shfl_xor(v, 1);  v += __shfl_xor(v, 2);  v += __shfl_xor(v, 4);
    v += __shfl_xor(v, 8);  v += __shfl_xor(v, 16); v += __shfl_xor(v, 32);
    return v;
}
__device__ __forceinline__ float tanh_fast(float x) {
    float e = __expf(2.f * x);
    return 1.f - 2.f / (e + 1.f);
}

// 2 waves per batch element (K-split); block = 4 waves = 2 elements; grid = 512 -> 2 blocks/CU.
__global__ __launch_bounds__(256, 2)
void node_fused2(const float* __restrict__ x,
                 const float* __restrict__ iw1, const float* __restrict__ ib1,
                 const float* __restrict__ iw2, const float* __restrict__ ib2,
                 const float* __restrict__ ow1, const float* __restrict__ ob1,
                 const float* __restrict__ ow2, const float* __restrict__ ob2,
                 const float* __restrict__ inter, const float* __restrict__ cons,
                 const float* __restrict__ dw1, const float* __restrict__ db1,
                 const float* __restrict__ dw2, const float* __restrict__ db2,
                 const float* __restrict__ tpts,
                 float* __restrict__ out)
{
    extern __shared__ float sm[];
    const int tid = threadIdx.x;
    const int w   = tid >> 6;        // wave 0..3
    const int ln  = tid & 63;        // lane
    const int p   = w >> 1;          // element within block (0/1)
    const int hf  = w & 1;           // K-split half (0/1)
    const int b   = blockIdx.x * 2 + p;

    float* W1s   = sm + OFF_W1;              // [64][256] (rows 64,65 kept in regs)
    float* hidw  = sm + OFF_HIDW + w * 384;  // this wave's [3][128] hidden slice
    float* parts = sm + OFF_PARTS;           // [2][4][3][64] d-partials (double buffered)
    float* decd  = sm + OFF_DECD;            // [4][3][64] decode partials
    float* tps   = sm + OFF_TPS;             // [96]

    // ---- stage W1 rows 0..63 into LDS (coalesced) ----
    for (int idx = tid; idx < HD * NH; idx += 256) W1s[idx] = ow1[idx];
    if (tid < TPTS) tps[tid] = tpts[tid];

    // ---- persistent per-thread constants ----
    const int   c0   = 128 * hf + 2 * ln;          // my two hidden columns: c0, c0+1
    const float w64a = ow1[64 * NH + c0], w64b = ow1[64 * NH + c0 + 1];  // ie feature row
    const float w65a = ow1[65 * NH + c0], w65b = ow1[65 * NH + c0 + 1];  // t feature row
    const float b1a  = ob1[c0], b1b = ob1[c0 + 1];
    const float b2c  = ob2[ln];
    const float db1r0 = db1[ln], db1r1 = db1[64 + ln], db1r2 = db1[128 + ln];

    // W2 half-columns in registers: w2r[j] = W2[128*hf + j][ln]
    float w2r[128];
    #pragma unroll
    for (int j = 0; j < 128; ++j) w2r[j] = ow2[(128 * hf + j) * HD + ln];

    // M = conservation @ interaction (3x3)
    float M00,M01,M02,M10,M11,M12,M20,M21,M22;
    {
        float I0=inter[0],I1=inter[1],I2=inter[2],I3=inter[3],I4=inter[4];
        float I5=inter[5],I6=inter[6],I7=inter[7],I8=inter[8];
        float C0=cons[0],C1=cons[1],C2=cons[2],C3=cons[3],C4=cons[4];
        float C5=cons[5],C6=cons[6],C7=cons[7],C8=cons[8];
        M00=C0*I0+C1*I3+C2*I6; M01=C0*I1+C1*I4+C2*I7; M02=C0*I2+C1*I5+C2*I8;
        M10=C3*I0+C4*I3+C5*I6; M11=C3*I1+C4*I4+C5*I7; M12=C3*I2+C4*I5+C5*I8;
        M20=C6*I0+C7*I3+C8*I6; M21=C6*I1+C7*I4+C8*I7; M22=C6*I2+C7*I5+C8*I8;
    }

    // ---- initial state (computed redundantly by both waves of the pair) ----
    float xs[7];
    {
        const float* xp = x + (size_t)b * TPTS * NV + ln * NV;   // t = ln
        #pragma unroll
        for (int v = 0; v < 7; ++v) xs[v] = xp[v];
        if (ln < 32) {                                           // t = 64 + ln
            const float* xp2 = xp + 64 * NV;
            #pragma unroll
            for (int v = 0; v < 7; ++v) xs[v] += xp2[v];
        }
        #pragma unroll
        for (int v = 0; v < 7; ++v) xs[v] = wsum64(xs[v]) * (1.f / 96.f);
    }
    float h0v;
    {
        float a = ib1[ln];
        #pragma unroll
        for (int v = 0; v < 7; ++v) a = fmaf(xs[v], iw1[v * HD + ln], a);
        h0v = fmaxf(a, 0.f);
    }
    float yb0, yb1, yb2;
    {
        float a0 = ib2[ln], a1 = ib2[64 + ln], a2 = ib2[128 + ln];
        #pragma unroll 16
        for (int k = 0; k < 64; ++k) {
            float hk = rdlane(h0v, k);
            a0 = fmaf(hk, iw2[k * 192 + ln], a0);
            a1 = fmaf(hk, iw2[k * 192 + 64 + ln], a1);
            a2 = fmaf(hk, iw2[k * 192 + 128 + ln], a2);
        }
        yb0 = a0; yb1 = a1; yb2 = a2;
    }
    __syncthreads();   // W1s / tps ready

    // ---- one ODE-func eval (this wave computes its K-half; exchange via parts[par]) ----
    auto eval_f = [&](float ts, float ys0, float ys1, float ys2,
                      float& d0, float& d1, float& d2, int par) {
        // component means -> interaction effect (wave-uniform, identical in both waves)
        float s0 = wsum64(ys0) * (1.f / 64.f);
        float s1 = wsum64(ys1) * (1.f / 64.f);
        float s2 = wsum64(ys2) * (1.f / 64.f);
        float e0 = fmaf(M02, s2, fmaf(M01, s1, M00 * s0));
        float e1 = fmaf(M12, s2, fmaf(M11, s1, M10 * s0));
        float e2 = fmaf(M22, s2, fmaf(M21, s1, M20 * s0));
        // layer 1: my 2 hidden cols x 3 rows
        float aA0 = fmaf(w64a, e0, fmaf(w65a, ts, b1a));
        float aB0 = fmaf(w64b, e0, fmaf(w65b, ts, b1b));
        float aA1 = fmaf(w64a, e1, fmaf(w65a, ts, b1a));
        float aB1 = fmaf(w64b, e1, fmaf(w65b, ts, b1b));
        float aA2 = fmaf(w64a, e2, fmaf(w65a, ts, b1a));
        float aB2 = fmaf(w64b, e2, fmaf(w65b, ts, b1b));
        const float2* w1p = (const float2*)W1s + 64 * hf + ln;   // row stride 128 float2
        #pragma unroll
        for (int i = 0; i < 64; ++i) {
            float2 wv = w1p[i * 128];
            float yi0 = rdlane(ys0, i), yi1 = rdlane(ys1, i), yi2 = rdlane(ys2, i);
            aA0 = fmaf(yi0, wv.x, aA0); aB0 = fmaf(yi0, wv.y, aB0);
            aA1 = fmaf(yi1, wv.x, aA1); aB1 = fmaf(yi1, wv.y, aB1);
            aA2 = fmaf(yi2, wv.x, aA2); aB2 = fmaf(yi2, wv.y, aB2);
        }
        // tanh, stash hidden slice in this wave's private LDS region (wave-local RAW, no barrier)
        float2 hp0, hp1, hp2;
        hp0.x = tanh_fast(aA0); hp0.y = tanh_fast(aB0);
        hp1.x = tanh_fast(aA1); hp1.y = tanh_fast(aB1);
        hp2.x = tanh_fast(aA2); hp2.y = tanh_fast(aB2);
        ((float2*)(hidw      ))[ln] = hp0;
        ((float2*)(hidw + 128))[ln] = hp1;
        ((float2*)(hidw + 256))[ln] = hp2;
        // layer 2 partial: out col = ln, K over my 128 hidden cols (W2 from registers)
        float p0 = 0.f, p1 = 0.f, p2 = 0.f;
        const float4* hq0 = (const float4*)(hidw);
        const float4* hq1 = (const float4*)(hidw + 128);
        const float4* hq2 = (const float4*)(hidw + 256);
        #pragma unroll
        for (int q = 0; q < 32; ++q) {
            float4 u0 = hq0[q], u1 = hq1[q], u2 = hq2[q];
            p0 = fmaf(u0.w, w2r[4*q+3], fmaf(u0.z, w2r[4*q+2], fmaf(u0.y, w2r[4*q+1], fmaf(u0.x, w2r[4*q], p0))));
            p1 = fmaf(u1.w, w2r[4*q+3], fmaf(u1.z, w2r[4*q+2], fmaf(u1.y, w2r[4*q+1], fmaf(u1.x, w2r[4*q], p1))));
            p2 = fmaf(u2.w, w2r[4*q+3], fmaf(u2.z, w2r[4*q+2], fmaf(u2.y, w2r[4*q+1], fmaf(u2.x, w2r[4*q], p2))));
        }
        // exchange partials with pair wave (double-buffered by par)
        float* mp = parts + (par * 4 + w) * 192 + ln;
        mp[0] = p0; mp[64] = p1; mp[128] = p2;
        __syncthreads();
        const float* op = parts + (par * 4 + (w ^ 1)) * 192 + ln;
        d0 = p0 + op[0]   + b2c;     // commutative adds -> bitwise identical in both waves
        d1 = p1 + op[64]  + b2c;
        d2 = p2 + op[128] + b2c;
    };

    // ---- fused per-component decode of current state (yb regs) at time index tix ----
    auto decode = [&](int tix) {
        float q0 = 0.f, q1 = 0.f, q2 = 0.f;
        const int hb = 32 * hf;
        #pragma unroll 8
        for (int m = 0; m < 32; ++m) {
            int hh = hb + m;
            float y0h = rdlane(yb0, hh), y1h = rdlane(yb1, hh), y2h = rdlane(yb2, hh);
            q0 = fmaf(y0h, dw1[hh * HD + ln], q0);
            q1 = fmaf(y1h, dw1[(64 + hh) * HD + ln], q1);
            q2 = fmaf(y2h, dw1[(128 + hh) * HD + ln], q2);
        }
        float* md = decd + w * 192 + ln;
        md[0] = q0; md[64] = q1; md[128] = q2;
        __syncthreads();
        const float* od = decd + (w ^ 1) * 192 + ln;
        float h2a = fmaxf(q0 + od[0]   + db1r0, 0.f);
        float h2b = fmaxf(q1 + od[64]  + db1r1, 0.f);
        float h2c = fmaxf(q2 + od[128] + db1r2, 0.f);
        // decode layer 2: 21 (c,v) outputs split 11/10 across the pair's waves
        const int i0 = hf ? 11 : 0, i1 = hf ? 21 : 11;
        for (int i = i0; i < i1; ++i) {
            int c = i / 7, v = i - 7 * c;
            float hv = (c == 0) ? h2a : ((c == 1) ? h2b : h2c);
            float pv = hv * dw2[(c * HD + ln) * NV + v];
            pv = wsum64(pv);
            if (ln == 0)
                out[(((size_t)c * BTOT + b) * TPTS + tix) * NV + v] = pv + db2[c * NV + v];
        }
    };

    // ---- RK4 over 95 intervals ----
    float d0, d1, d2;
    decode(0);
    #pragma unroll 1
    for (int s = 0; s < TPTS - 1; ++s) {
        const float t0 = tps[s], t1 = tps[s + 1];
        const float dt = t1 - t0, hdt = 0.5f * dt;

        eval_f(t0, yb0, yb1, yb2, d0, d1, d2, 0);
        float k0 = d0, k1 = d1, k2 = d2;

        eval_f(t0 + hdt, fmaf(hdt, d0, yb0), fmaf(hdt, d1, yb1), fmaf(hdt, d2, yb2),
               d0, d1, d2, 1);
        k0 += 2.f * d0; k1 += 2.f * d1; k2 += 2.f * d2;

        eval_f(t0 + hdt, fmaf(hdt, d0, yb0), fmaf(hdt, d1, yb1), fmaf(hdt, d2, yb2),
               d0, d1, d2, 0);
        k0 += 2.f * d0; k1 += 2.f * d1; k2 += 2.f * d2;

        eval_f(t1, fmaf(dt, d0, yb0), fmaf(dt, d1, yb1), fmaf(dt, d2, yb2),
               d0, d1, d2, 1);
        k0 += d0; k1 += d1; k2 += d2;

        const float c6 = dt * (1.f / 6.f);
        yb0 = fmaf(c6, k0, yb0); yb1 = fmaf(c6, k1, yb1); yb2 = fmaf(c6, k2, yb2);

        decode(s + 1);
    }
}

extern "C" void kernel_launch(void* const* d_in, const int* in_sizes, int n_in,
                              void* d_out, int out_size, void* d_ws, size_t ws_size,
                              hipStream_t stream) {
    const float* x     = (const float*)d_in[0];
    const float* iw1   = (const float*)d_in[1];
    const float* ib1   = (const float*)d_in[2];
    const float* iw2   = (const float*)d_in[3];
    const float* ib2   = (const float*)d_in[4];
    const float* ow1   = (const float*)d_in[5];
    const float* ob1   = (const float*)d_in[6];
    const float* ow2   = (const float*)d_in[7];
    const float* ob2   = (const float*)d_in[8];
    const float* inter = (const float*)d_in[9];
    const float* cons  = (const float*)d_in[10];
    const float* dw1   = (const float*)d_in[11];
    const float* db1   = (const float*)d_in[12];
    const float* dw2   = (const float*)d_in[13];
    const float* db2   = (const float*)d_in[14];
    const float* tpts  = (const float*)d_in[15];
    float* out = (float*)d_out;

    (void)hipFuncSetAttribute((const void*)node_fused2,
                              hipFuncAttributeMaxDynamicSharedMemorySize,
                              SMEM_BYTES);

    node_fused2<<<BTOT / 2, 256, SMEM_BYTES, stream>>>(
        x, iw1, ib1, iw2, ib2, ow1, ob1, ow2, ob2,
        inter, cons, dw1, db1, dw2, db2, tpts, out);
}

// Round 3
// 3205.306 us; speedup vs baseline: 3.3971x; 3.3971x over previous
//
#include <hip/hip_runtime.h>

// Problem constants
#define BTOT 1024
#define TPTS 96
#define NV   7
#define HD   64
#define NH   256   // ode hidden (4*H)

// LDS layout (float offsets), total 39008 floats = 156032 B (one block per CU)
#define OFF_W1    0        // [64][256]              = 16384
#define OFF_W2    16384    // [256][64]              = 16384
#define OFF_PARTS 32768    // [2 parity][4 el][4 q][3][64] = 6144
#define OFF_TPS   38912    // 96
#define SMEM_FLOATS 39008
#define SMEM_BYTES  (SMEM_FLOATS * 4)

__device__ __forceinline__ float rdlane(float v, int i) {
    return __int_as_float(__builtin_amdgcn_readlane(__float_as_int(v), i));
}
__device__ __forceinline__ float wsum64(float v) {
    v += __shfl_xor(v, 1);  v += __shfl_xor(v, 2);  v += __shfl_xor(v, 4);
    v += __shfl_xor(v, 8);  v += __shfl_xor(v, 16); v += __shfl_xor(v, 32);
    return v;
}
__device__ __forceinline__ float tanh_fast(float x) {
    float e = __expf(2.f * x);
    return 1.f - 2.f / (e + 1.f);
}

// 4 waves per batch element; block = 1024 thr = 16 waves = 4 elements; grid = 256 (1 block/CU).
// All state in named registers (redundant across an element's 4 waves); weights in LDS;
// one barrier per ODE-func eval.
__global__ __launch_bounds__(1024, 4)
void node_fused3(const float* __restrict__ x,
                 const float* __restrict__ iw1, const float* __restrict__ ib1,
                 const float* __restrict__ iw2, const float* __restrict__ ib2,
                 const float* __restrict__ ow1, const float* __restrict__ ob1,
                 const float* __restrict__ ow2, const float* __restrict__ ob2,
                 const float* __restrict__ inter, const float* __restrict__ cons,
                 const float* __restrict__ dw1, const float* __restrict__ db1,
                 const float* __restrict__ dw2, const float* __restrict__ db2,
                 const float* __restrict__ tpts,
                 float* __restrict__ out)
{
    extern __shared__ float sm[];
    float* W1s   = sm + OFF_W1;      // [i][col] i<64
    float* W2s   = sm + OFF_W2;      // [k][out]
    float* parts = sm + OFF_PARTS;   // [par][el][q][r][64]
    float* tps   = sm + OFF_TPS;

    const int tid = threadIdx.x;
    const int w   = tid >> 6;        // wave 0..15
    const int ln  = tid & 63;
    const int el  = w >> 2;          // element within block 0..3
    const int q   = w & 3;           // quarter (K-chunk / hidden-col group)
    const int b   = blockIdx.x * 4 + el;
    const int c   = q * 64 + ln;     // my hidden column in [0,256)

    // ---- stage weights into LDS (coalesced, 16 floats per thread each) ----
    for (int idx = tid; idx < HD * NH; idx += 1024) {
        W1s[idx] = ow1[idx];         // rows 0..63 of ode_w1
        W2s[idx] = ow2[idx];         // [256][64] natural
    }
    if (tid < TPTS) tps[tid] = tpts[tid];

    // ---- per-thread constants ----
    const float w64c = ow1[64 * NH + c];   // ie feature weight for my column
    const float w65c = ow1[65 * NH + c];   // t feature weight
    const float b1c  = ob1[c];
    const float b2c  = ob2[ln];
    const float db1c = (q < 3) ? db1[q * HD + ln] : 0.f;

    // M = conservation @ interaction (3x3)
    float M00,M01,M02,M10,M11,M12,M20,M21,M22;
    {
        float I0=inter[0],I1=inter[1],I2=inter[2],I3=inter[3],I4=inter[4];
        float I5=inter[5],I6=inter[6],I7=inter[7],I8=inter[8];
        float C0=cons[0],C1=cons[1],C2=cons[2],C3=cons[3],C4=cons[4];
        float C5=cons[5],C6=cons[6],C7=cons[7],C8=cons[8];
        M00=C0*I0+C1*I3+C2*I6; M01=C0*I1+C1*I4+C2*I7; M02=C0*I2+C1*I5+C2*I8;
        M10=C3*I0+C4*I3+C5*I6; M11=C3*I1+C4*I4+C5*I7; M12=C3*I2+C4*I5+C5*I8;
        M20=C6*I0+C7*I3+C8*I6; M21=C6*I1+C7*I4+C8*I7; M22=C6*I2+C7*I5+C8*I8;
    }

    // ---- initial state (redundant across the element's 4 waves; bitwise identical) ----
    float xs0,xs1,xs2,xs3,xs4,xs5,xs6;
    {
        const float* xp = x + (size_t)b * TPTS * NV + ln * NV;     // t = ln
        float v0=xp[0],v1=xp[1],v2=xp[2],v3=xp[3],v4=xp[4],v5=xp[5],v6=xp[6];
        if (ln < 32) {                                             // t = 64 + ln
            const float* xp2 = xp + 64 * NV;
            v0+=xp2[0]; v1+=xp2[1]; v2+=xp2[2]; v3+=xp2[3]; v4+=xp2[4]; v5+=xp2[5]; v6+=xp2[6];
        }
        xs0=wsum64(v0)*(1.f/96.f); xs1=wsum64(v1)*(1.f/96.f); xs2=wsum64(v2)*(1.f/96.f);
        xs3=wsum64(v3)*(1.f/96.f); xs4=wsum64(v4)*(1.f/96.f); xs5=wsum64(v5)*(1.f/96.f);
        xs6=wsum64(v6)*(1.f/96.f);
    }
    float h0v;
    {
        float a = ib1[ln];
        a = fmaf(xs0, iw1[0*HD+ln], a); a = fmaf(xs1, iw1[1*HD+ln], a);
        a = fmaf(xs2, iw1[2*HD+ln], a); a = fmaf(xs3, iw1[3*HD+ln], a);
        a = fmaf(xs4, iw1[4*HD+ln], a); a = fmaf(xs5, iw1[5*HD+ln], a);
        a = fmaf(xs6, iw1[6*HD+ln], a);
        h0v = fmaxf(a, 0.f);
    }
    float yb0, yb1, yb2;
    {
        float a0 = ib2[ln], a1 = ib2[64 + ln], a2 = ib2[128 + ln];
        #pragma unroll
        for (int k = 0; k < 64; ++k) {
            float hk = rdlane(h0v, k);
            a0 = fmaf(hk, iw2[k * 192 + ln], a0);
            a1 = fmaf(hk, iw2[k * 192 + 64 + ln], a1);
            a2 = fmaf(hk, iw2[k * 192 + 128 + ln], a2);
        }
        yb0 = a0; yb1 = a1; yb2 = a2;
    }
    __syncthreads();   // LDS weights ready

    // ---- one ODE-func eval; ONE barrier; parity double-buffers the partial exchange ----
    auto eval_f = [&](float ts, float ys0, float ys1, float ys2, int par,
                      float& d0, float& d1, float& d2) {
        // component means -> interaction effects (identical across the element's waves)
        float s0 = wsum64(ys0) * (1.f / 64.f);
        float s1 = wsum64(ys1) * (1.f / 64.f);
        float s2 = wsum64(ys2) * (1.f / 64.f);
        float e0 = fmaf(M02, s2, fmaf(M01, s1, M00 * s0));
        float e1 = fmaf(M12, s2, fmaf(M11, s1, M10 * s0));
        float e2 = fmaf(M22, s2, fmaf(M21, s1, M20 * s0));
        // layer 1: my hidden column c, 3 rows
        float a0 = fmaf(w64c, e0, fmaf(w65c, ts, b1c));
        float a1 = fmaf(w64c, e1, fmaf(w65c, ts, b1c));
        float a2 = fmaf(w64c, e2, fmaf(w65c, ts, b1c));
        #pragma unroll
        for (int i = 0; i < 64; ++i) {
            float wv = W1s[i * NH + c];                 // lane-contiguous, conflict-free
            a0 = fmaf(rdlane(ys0, i), wv, a0);
            a1 = fmaf(rdlane(ys1, i), wv, a1);
            a2 = fmaf(rdlane(ys2, i), wv, a2);
        }
        float t0 = tanh_fast(a0), t1 = tanh_fast(a1), t2 = tanh_fast(a2);
        // layer 2: wave q's K-chunk is exactly its own tanh outputs -> readlane, no LDS handoff
        float p0 = 0.f, p1 = 0.f, p2 = 0.f;
        #pragma unroll
        for (int k = 0; k < 64; ++k) {
            float wv = W2s[(q * 64 + k) * HD + ln];     // lane-contiguous, conflict-free
            p0 = fmaf(rdlane(t0, k), wv, p0);
            p1 = fmaf(rdlane(t1, k), wv, p1);
            p2 = fmaf(rdlane(t2, k), wv, p2);
        }
        // exchange partials across the element's 4 waves
        float* mp = parts + ((par * 4 + el) * 4 + q) * 192 + ln;
        mp[0] = p0; mp[64] = p1; mp[128] = p2;
        __syncthreads();
        const float* rp = parts + (par * 4 + el) * 768 + ln;
        d0 = b2c + rp[0]   + rp[192]     + rp[384]     + rp[576];
        d1 = b2c + rp[64]  + rp[192+64]  + rp[384+64]  + rp[576+64];
        d2 = b2c + rp[128] + rp[192+128] + rp[384+128] + rp[576+128];
    };

    // ---- fused decode of committed state yb at time index tix (no barrier, no LDS) ----
    auto decode = [&](int tix) {
        if (q < 3) {
            const int cc = q;                              // component = quarter 0..2
            const float yr = (cc == 0) ? yb0 : ((cc == 1) ? yb1 : yb2);
            float acc = db1c;
            const float* wp = dw1 + (size_t)cc * HD * HD + ln;
            #pragma unroll
            for (int h = 0; h < 64; ++h)
                acc = fmaf(rdlane(yr, h), wp[h * HD], acc);
            float hid = fmaxf(acc, 0.f);
            const float* w2p = dw2 + ((size_t)cc * HD + ln) * NV;
            #pragma unroll
            for (int v = 0; v < NV; ++v) {
                float pv = wsum64(hid * w2p[v]);
                if (ln == 0)
                    out[(((size_t)cc * BTOT + b) * TPTS + tix) * NV + v] = pv + db2[cc * NV + v];
            }
        }
    };

    // ---- RK4 over 95 intervals ----
    decode(0);
    float d0, d1, d2;
    #pragma unroll 1
    for (int s = 0; s < TPTS - 1; ++s) {
        const float ta = tps[s], tb = tps[s + 1];
        const float dt = tb - ta, hdt = 0.5f * dt;

        eval_f(ta, yb0, yb1, yb2, 0, d0, d1, d2);
        float k0 = d0, k1 = d1, k2 = d2;

        eval_f(ta + hdt, fmaf(hdt, d0, yb0), fmaf(hdt, d1, yb1), fmaf(hdt, d2, yb2),
               1, d0, d1, d2);
        k0 += 2.f * d0; k1 += 2.f * d1; k2 += 2.f * d2;

        eval_f(ta + hdt, fmaf(hdt, d0, yb0), fmaf(hdt, d1, yb1), fmaf(hdt, d2, yb2),
               0, d0, d1, d2);
        k0 += 2.f * d0; k1 += 2.f * d1; k2 += 2.f * d2;

        eval_f(tb, fmaf(dt, d0, yb0), fmaf(dt, d1, yb1), fmaf(dt, d2, yb2),
               1, d0, d1, d2);
        k0 += d0; k1 += d1; k2 += d2;

        const float c6 = dt * (1.f / 6.f);
        yb0 = fmaf(c6, k0, yb0); yb1 = fmaf(c6, k1, yb1); yb2 = fmaf(c6, k2, yb2);

        decode(s + 1);
    }
}

extern "C" void kernel_launch(void* const* d_in, const int* in_sizes, int n_in,
                              void* d_out, int out_size, void* d_ws, size_t ws_size,
                              hipStream_t stream) {
    const float* x     = (const float*)d_in[0];
    const float* iw1   = (const float*)d_in[1];
    const float* ib1   = (const float*)d_in[2];
    const float* iw2   = (const float*)d_in[3];
    const float* ib2   = (const float*)d_in[4];
    const float* ow1   = (const float*)d_in[5];
    const float* ob1   = (const float*)d_in[6];
    const float* ow2   = (const float*)d_in[7];
    const float* ob2   = (const float*)d_in[8];
    const float* inter = (const float*)d_in[9];
    const float* cons  = (const float*)d_in[10];
    const float* dw1   = (const float*)d_in[11];
    const float* db1   = (const float*)d_in[12];
    const float* dw2   = (const float*)d_in[13];
    const float* db2   = (const float*)d_in[14];
    const float* tpts  = (const float*)d_in[15];
    float* out = (float*)d_out;

    (void)hipFuncSetAttribute((const void*)node_fused3,
                              hipFuncAttributeMaxDynamicSharedMemorySize,
                              SMEM_BYTES);

    node_fused3<<<BTOT / 4, 1024, SMEM_BYTES, stream>>>(
        x, iw1, ib1, iw2, ib2, ow1, ob1, ow2, ob2,
        inter, cons, dw1, db1, dw2, db2, tpts, out);
}